// Round 7
// baseline (331.424 us; speedup 1.0000x reference)
//
#include <hip/hip_runtime.h>
#include <hip/hip_bf16.h>

// Problem constants: B=2, T=2048, D=1024, H=16, DK=64
// Math reduction: y = permute(x @ Wv) @ Wo^T  (softmax rowsum == 1 exactly;
// reference's einsum 'bhtl,bthd->bhtd' never contracts v with A over l, so
// o[b,h,t,:] = (sum_l A[b,h,t,l]) * v[b,t,h,:] = v[b,t,h,:]).
// Permute: V[b*2048+t][h*64+k] -> Vp[b*2048 + h*128 + t/16][(t%16)*64 + k]
// Inputs/outputs FP32 (reference dtype); internal bf16 MFMA, fp32 accum.
// R6: single persistent dispatch (prep -> gridbar -> gemm1 -> gridbar ->
// gemm2); R6 run PROVED barriers + phases execute (absmax was tiny-nonzero,
// not stub-zero) but x-conversion only covered 1/4 of x (2 iters, needed 8).
// R7: fix coverage: 512 blk x 8 iters x 256 thr = 1,048,576 float4 = |x|/4.

using bf16 = __hip_bfloat16;
typedef __attribute__((ext_vector_type(8))) short bf16x8;   // 8 bf16 = 4 VGPRs
typedef __attribute__((ext_vector_type(4))) float f32x4;

#define NBLK 512

__device__ __forceinline__ void gld_lds16(const void* g, void* l) {
    // async global->LDS, 16B/lane; LDS dest = wave-uniform base + lane*16
    __builtin_amdgcn_global_load_lds(
        (const __attribute__((address_space(1))) void*)g,
        (__attribute__((address_space(3))) void*)l, 16, 0, 0);
}

__device__ __forceinline__ void grid_barrier(int* cnt) {
    __syncthreads();                 // all block threads done with prior phase
    __threadfence();                 // release: writes visible device-wide
    if (threadIdx.x == 0) {
        __hip_atomic_fetch_add(cnt, 1, __ATOMIC_ACQ_REL, __HIP_MEMORY_SCOPE_AGENT);
        while (__hip_atomic_load(cnt, __ATOMIC_ACQUIRE, __HIP_MEMORY_SCOPE_AGENT) < NBLK)
            __builtin_amdgcn_s_sleep(2);
    }
    __syncthreads();
    __threadfence();                 // acquire for all threads (L1/L2 inval)
}

__device__ __forceinline__ void storeC(float v, bf16* p)  { *p = __float2bfloat16(v); }
__device__ __forceinline__ void storeC(float v, float* p) { *p = v; }

// ---------------- GEMM tile  C = A(..x1024) * Bt(..x1024)^T ----------------
// 128x64 tile / 256 threads; 4 waves 2x2, each 64x32 = 4x2 accs; dbuf LDS,
// distance-1 DMA prefetch, XOR-swizzled chunk slots (R4/R5-verified body).
template <bool PERMUTE, typename OutT>
__device__ __forceinline__ void gemm_body(const bf16* __restrict__ A,
                                          const bf16* __restrict__ Bt,
                                          OutT* __restrict__ C,
                                          int bx, int by,
                                          bf16 (*st)[6144], int tid) {
    const int wave = tid >> 6;
    const int lane = tid & 63;
    const int m0 = bx * 128;
    const int n0 = by * 64;
    const int wr = (wave >> 1) * 64;
    const int wc = (wave & 1) * 32;

    // staging: thread t covers tile row tid>>2, 16B chunk slot tid&3.
    // Swizzle: slot s of row r holds global chunk g = s ^ ((r>>1)&3).
    const int srow = tid >> 2;
    const int scol = (((tid & 3) ^ ((tid >> 3) & 3)) & 3) * 8;
    const bf16* gA = A  + (size_t)(m0 + srow) * 1024 + scol;
    const bf16* gB = Bt + (size_t)(n0 + srow) * 1024 + scol;
    const int woff = wave * 512;

    f32x4 acc[4][2];
#pragma unroll
    for (int i = 0; i < 4; ++i)
#pragma unroll
        for (int j = 0; j < 2; ++j)
            acc[i][j] = (f32x4){0.f, 0.f, 0.f, 0.f};

    const int fr = lane & 15;
    const int q8 = ((((lane >> 4) ^ (lane >> 1)) & 3)) * 8;  // swizzled slot

    {   // prefetch iter 0 into buf 0
        bf16* s = st[0];
        gld_lds16(gA,             s + woff);
        gld_lds16(gA + 64 * 1024, s + 2048 + woff);
        gld_lds16(gB,             s + 4096 + woff);
    }

    for (int i = 0; i < 32; ++i) {
        __syncthreads();              // drains vmcnt -> buf i&1 visible
        if (i < 31) {                 // prefetch iter i+1 into other buf
            const int kt = (i + 1) * 32;
            bf16* s = st[(i + 1) & 1];
            gld_lds16(gA + kt,             s + woff);
            gld_lds16(gA + kt + 64 * 1024, s + 2048 + woff);
            gld_lds16(gB + kt,             s + 4096 + woff);
        }
        const bf16* sAb = st[i & 1];
        const bf16* sBb = st[i & 1] + 4096;
        bf16x8 aF[4], bF[2];
#pragma unroll
        for (int ii = 0; ii < 4; ++ii)
            aF[ii] = *(const bf16x8*)&sAb[(wr + ii * 16 + fr) * 32 + q8];
#pragma unroll
        for (int j = 0; j < 2; ++j)
            bF[j] = *(const bf16x8*)&sBb[(wc + j * 16 + fr) * 32 + q8];
#pragma unroll
        for (int ii = 0; ii < 4; ++ii)
#pragma unroll
            for (int j = 0; j < 2; ++j)
                acc[ii][j] = __builtin_amdgcn_mfma_f32_16x16x32_bf16(
                    aF[ii], bF[j], acc[ii][j], 0, 0, 0);
    }

    // epilogue: C/D layout col=lane&15, row=(lane>>4)*4+reg  [m91-verified]
#pragma unroll
    for (int i = 0; i < 4; ++i) {
#pragma unroll
        for (int j = 0; j < 2; ++j) {
            const int col = n0 + wc + j * 16 + (lane & 15);
#pragma unroll
            for (int r = 0; r < 4; ++r) {
                const int row = m0 + wr + i * 16 + (lane >> 4) * 4 + r;
                if (PERMUTE) {
                    const int b = row >> 11, t = row & 2047;
                    const int h = col >> 6,  k = col & 63;
                    const int rr = (b << 11) | (h << 7) | (t >> 4);
                    const int cc = ((t & 15) << 6) | k;
                    storeC(acc[i][j][r], &C[(size_t)rr * 1024 + cc]);
                } else {
                    storeC(acc[i][j][r], &C[(size_t)row * 1024 + col]);
                }
            }
        }
    }
}

// ---------------- fused persistent kernel ----------------------------------
__global__ __launch_bounds__(256, 2)
void fused_mha(const float* __restrict__ x, const float* __restrict__ Wv,
               const float* __restrict__ Wo,
               bf16* __restrict__ xb, bf16* __restrict__ WvT,
               bf16* __restrict__ Wob, bf16* __restrict__ vperm,
               float* __restrict__ out, int* __restrict__ sync) {
    __shared__ __align__(16) bf16 st[2][6144];    // 24 KB; phase-0 aliases it
    const int id  = blockIdx.x;
    const int tid = threadIdx.x;

    // ---- phase 0: x cvt (all blocks), Wv transpose (id<256), Wo cvt -------
    // x: 4096*1024 fp32 = 1,048,576 float4 = 512 blk * 8 iter * 256 thr
#pragma unroll
    for (int s = 0; s < 8; ++s) {
        const int i = id * 2048 + s * 256 + tid;
        const float4 v = ((const float4*)x)[i];
        bf16 o[4] = {__float2bfloat16(v.x), __float2bfloat16(v.y),
                     __float2bfloat16(v.z), __float2bfloat16(v.w)};
        ((ulong1*)xb)[i] = *(ulong1*)o;
    }
    if (id < 256) {                               // Wv 64x64 transpose tile
        float (*tile)[65] = (float(*)[65])st;     // 16.6 KB <= 24 KB
        const int bx = id & 15, by = id >> 4;
        const int c = tid & 63, r4 = tid >> 6;
#pragma unroll
        for (int p = 0; p < 16; ++p) {
            int r = p * 4 + r4;
            tile[r][c] = Wv[(size_t)(by * 64 + r) * 1024 + bx * 64 + c];
        }
        __syncthreads();
#pragma unroll
        for (int p = 0; p < 16; ++p) {
            int r = p * 4 + r4;
            WvT[(size_t)(bx * 64 + r) * 1024 + by * 64 + c] = __float2bfloat16(tile[c][r]);
        }
    } else {                                      // Wo: 262,144 float4 total
#pragma unroll
        for (int s = 0; s < 4; ++s) {
            const int i = (id - 256) * 1024 + s * 256 + tid;
            const float4 v = ((const float4*)Wo)[i];
            bf16 o[4] = {__float2bfloat16(v.x), __float2bfloat16(v.y),
                         __float2bfloat16(v.z), __float2bfloat16(v.w)};
            ((ulong1*)Wob)[i] = *(ulong1*)o;
        }
    }

    grid_barrier(sync + 0);

    // ---- phase 1: vperm = permute(xb @ WvT^T), 32x16 tiles ----------------
    gemm_body<true, bf16>(xb, WvT, vperm, id & 31, id >> 5, st, tid);

    grid_barrier(sync + 16);

    // ---- phase 2: out = vperm @ Wob^T -------------------------------------
    gemm_body<false, float>(vperm, Wob, out, id & 31, id >> 5, st, tid);
}

extern "C" void kernel_launch(void* const* d_in, const int* in_sizes, int n_in,
                              void* d_out, int out_size, void* d_ws, size_t ws_size,
                              hipStream_t stream) {
    (void)in_sizes; (void)n_in; (void)out_size; (void)ws_size;
    // inputs (fp32): x, mask, Wq, Wk, Wv, Wo  (mask/Wq/Wk dead — see header)
    const float* x  = (const float*)d_in[0];
    const float* Wv = (const float*)d_in[4];
    const float* Wo = (const float*)d_in[5];
    float* out = (float*)d_out;

    int*  sync  = (int*)d_ws;                     // 2 counters (ws poisoned)
    bf16* xb    = (bf16*)((char*)d_ws + 256);     // 8 MB
    bf16* WvT   = xb  + 4096 * 1024;              // 2 MB
    bf16* Wob   = WvT + 1024 * 1024;              // 2 MB
    bf16* vperm = Wob + 1024 * 1024;              // 8 MB  (total ~20 MB)

    hipMemsetAsync(d_ws, 0, 256, stream);         // zero barrier counters
    fused_mha<<<NBLK, 256, 0, stream>>>(x, Wv, Wo, xb, WvT, Wob, vperm, out, sync);
}

// Round 8
// 115.301 us; speedup vs baseline: 2.8744x; 2.8744x over previous
//
#include <hip/hip_runtime.h>
#include <hip/hip_bf16.h>

// Problem constants: B=2, T=2048, D=1024, H=16, DK=64
// Math reduction: y = permute(x @ Wv) @ Wo^T  (softmax rowsum == 1 exactly;
// reference's einsum 'bhtl,bthd->bhtd' never contracts v with A over l, so
// o[b,h,t,:] = (sum_l A[b,h,t,l]) * v[b,t,h,:] = v[b,t,h,:]).
// Permute: V[b*2048+t][h*64+k] -> Vp[b*2048 + h*128 + t/16][(t%16)*64 + k]
// Inputs/outputs FP32 (reference dtype); internal bf16 MFMA, fp32 accum.
// R7 postmortem: persistent-kernel grid barriers cost ~100us each (threadfence
// = per-wave L2 wb/inv on non-coherent XCDs) -> reverted to 3 dispatches.
// Fixed harness overhead measured at ~64us; kernel-sum ~51us is the target.
// R8: TRIPLE-buffered LDS + raw-asm barrier. __syncthreads drains vmcnt(0)
// including the just-issued prefetch (m97 plateau mechanism). Now: 2 batches
// in flight, `s_waitcnt vmcnt(3)` (oldest batch only) + raw `s_barrier`,
// batch i+2 issued AFTER the barrier (WAR-safe: buf (i+2)%3 last read at
// iter i-1; reads retire before barrier entry via lgkm-before-MFMA).

using bf16 = __hip_bfloat16;
typedef __attribute__((ext_vector_type(8))) short bf16x8;   // 8 bf16 = 4 VGPRs
typedef __attribute__((ext_vector_type(4))) float f32x4;

__device__ __forceinline__ void gld_lds16(const void* g, void* l) {
    // async global->LDS, 16B/lane; LDS dest = wave-uniform base + lane*16
    __builtin_amdgcn_global_load_lds(
        (const __attribute__((address_space(1))) void*)g,
        (__attribute__((address_space(3))) void*)l, 16, 0, 0);
}

// ---- fused prep: Wv transpose+cvt | x cvt | Wo cvt, one dispatch ----------
__global__ __launch_bounds__(256) void prep(const float* __restrict__ x,
                                            const float* __restrict__ Wv,
                                            const float* __restrict__ Wo,
                                            bf16* __restrict__ xb,
                                            bf16* __restrict__ WvT,
                                            bf16* __restrict__ Wob) {
    __shared__ float tile[64][65];
    const int id = blockIdx.x;
    const int t  = threadIdx.x;
    if (id < 256) {                       // Wv transpose+convert (64x64 tile)
        const int bx = id & 15, by = id >> 4;
        const int c = t & 63, r4 = t >> 6;
#pragma unroll
        for (int p = 0; p < 16; ++p) {
            int r = p * 4 + r4;
            tile[r][c] = Wv[(size_t)(by * 64 + r) * 1024 + bx * 64 + c];
        }
        __syncthreads();
#pragma unroll
        for (int p = 0; p < 16; ++p) {
            int r = p * 4 + r4;
            WvT[(size_t)(bx * 64 + r) * 1024 + by * 64 + c] = __float2bfloat16(tile[c][r]);
        }
    } else if (id < 4352) {               // x -> bf16, float4 per thread
        const int i = (id - 256) * 256 + t;
        const float4 v = ((const float4*)x)[i];
        bf16 o[4] = {__float2bfloat16(v.x), __float2bfloat16(v.y),
                     __float2bfloat16(v.z), __float2bfloat16(v.w)};
        ((ulong1*)xb)[i] = *(ulong1*)o;
    } else {                              // Wo -> bf16
        const int i = (id - 4352) * 256 + t;
        const float4 v = ((const float4*)Wo)[i];
        bf16 o[4] = {__float2bfloat16(v.x), __float2bfloat16(v.y),
                     __float2bfloat16(v.z), __float2bfloat16(v.w)};
        ((ulong1*)Wob)[i] = *(ulong1*)o;
    }
}

// ---------------- GEMM  C = A(Mx1024) * Bt(Nx1024)^T -----------------------
// A, Bt bf16 row-major [.][K]: both operands K-contiguous.
// 128x64 tile / 256 threads; 4 waves 2x2, each 64x32 = 4x2 accs.
// Triple-buffered LDS, 2 DMA batches in flight, raw s_barrier + vmcnt(3).
__device__ __forceinline__ void storeC(float v, bf16* p)  { *p = __float2bfloat16(v); }
__device__ __forceinline__ void storeC(float v, float* p) { *p = v; }

template <bool PERMUTE, typename OutT>
__global__ __launch_bounds__(256) void gemm_bt(const bf16* __restrict__ A,
                                               const bf16* __restrict__ Bt,
                                               OutT* __restrict__ C) {
    __shared__ __align__(16) bf16 st[3][6144];    // 3 x 12 KB = 36 KB

    const int tid  = threadIdx.x;
    const int wave = tid >> 6;
    const int lane = tid & 63;
    const int m0 = blockIdx.x * 128;
    const int n0 = blockIdx.y * 64;

    const int wr = (wave >> 1) * 64;      // wave quadrant of 128x64 tile
    const int wc = (wave & 1) * 32;

    // staging: thread t covers tile row tid>>2, 16B chunk slot tid&3.
    // Swizzle: slot s of row r holds global chunk g = s ^ ((r>>1)&3).
    const int srow = tid >> 2;
    const int scol = (((tid & 3) ^ ((tid >> 3) & 3)) & 3) * 8;
    const bf16* gA = A  + (size_t)(m0 + srow) * 1024 + scol;
    const bf16* gB = Bt + (size_t)(n0 + srow) * 1024 + scol;
    const int woff = wave * 512;          // elems, wave-uniform LDS base

    f32x4 acc[4][2];
#pragma unroll
    for (int i = 0; i < 4; ++i)
#pragma unroll
        for (int j = 0; j < 2; ++j)
            acc[i][j] = (f32x4){0.f, 0.f, 0.f, 0.f};

    const int fr = lane & 15;
    const int q8 = ((((lane >> 4) ^ (lane >> 1)) & 3)) * 8;  // swizzled slot

    // prologue: batches 0,1 -> bufs 0,1 (6 DMAs outstanding per wave)
#pragma unroll
    for (int b = 0; b < 2; ++b) {
        bf16* s = st[b];
        const int kt = b * 32;
        gld_lds16(gA + kt,             s + woff);
        gld_lds16(gA + kt + 64 * 1024, s + 2048 + woff);
        gld_lds16(gB + kt,             s + 4096 + woff);
    }

#pragma unroll 1
    for (int i = 0; i < 32; ++i) {
        if (i < 31)
            asm volatile("s_waitcnt vmcnt(3)" ::: "memory");   // oldest batch done
        else
            asm volatile("s_waitcnt vmcnt(0)" ::: "memory");   // final batch done
        asm volatile("s_barrier" ::: "memory");                // raw: no vmcnt(0) drain
        if (i < 30) {                     // batch i+2 -> buf (i+2)%3 (post-barrier: WAR-safe)
            const int kt = (i + 2) * 32;
            bf16* s = st[(i + 2) % 3];
            gld_lds16(gA + kt,             s + woff);
            gld_lds16(gA + kt + 64 * 1024, s + 2048 + woff);
            gld_lds16(gB + kt,             s + 4096 + woff);
        }

        const bf16* sAb = st[i % 3];
        const bf16* sBb = st[i % 3] + 4096;
        bf16x8 aF[4], bF[2];
#pragma unroll
        for (int ii = 0; ii < 4; ++ii)
            aF[ii] = *(const bf16x8*)&sAb[(wr + ii * 16 + fr) * 32 + q8];
#pragma unroll
        for (int j = 0; j < 2; ++j)
            bF[j] = *(const bf16x8*)&sBb[(wc + j * 16 + fr) * 32 + q8];
#pragma unroll
        for (int ii = 0; ii < 4; ++ii)
#pragma unroll
            for (int j = 0; j < 2; ++j)
                acc[ii][j] = __builtin_amdgcn_mfma_f32_16x16x32_bf16(
                    aF[ii], bF[j], acc[ii][j], 0, 0, 0);
    }

    // epilogue: C/D layout col=lane&15, row=(lane>>4)*4+reg  [m91-verified]
#pragma unroll
    for (int i = 0; i < 4; ++i) {
#pragma unroll
        for (int j = 0; j < 2; ++j) {
            const int col = n0 + wc + j * 16 + (lane & 15);
#pragma unroll
            for (int r = 0; r < 4; ++r) {
                const int row = m0 + wr + i * 16 + (lane >> 4) * 4 + r;
                if (PERMUTE) {
                    const int b = row >> 11, t = row & 2047;
                    const int h = col >> 6,  k = col & 63;
                    const int rr = (b << 11) | (h << 7) | (t >> 4);
                    const int cc = ((t & 15) << 6) | k;
                    storeC(acc[i][j][r], &C[(size_t)rr * 1024 + cc]);
                } else {
                    storeC(acc[i][j][r], &C[(size_t)row * 1024 + col]);
                }
            }
        }
    }
}

extern "C" void kernel_launch(void* const* d_in, const int* in_sizes, int n_in,
                              void* d_out, int out_size, void* d_ws, size_t ws_size,
                              hipStream_t stream) {
    (void)in_sizes; (void)n_in; (void)out_size; (void)ws_size;
    // inputs (fp32): x, mask, Wq, Wk, Wv, Wo  (mask/Wq/Wk dead — see header)
    const float* x  = (const float*)d_in[0];
    const float* Wv = (const float*)d_in[4];
    const float* Wo = (const float*)d_in[5];
    float* out = (float*)d_out;

    bf16* xb    = (bf16*)d_ws;                 // 4096*1024 bf16 = 8 MB
    bf16* WvT   = xb    + 4096 * 1024;         // 2 MB
    bf16* Wob   = WvT   + 1024 * 1024;         // 2 MB
    bf16* vperm = Wob   + 1024 * 1024;         // 8 MB   (total 20 MB)

    prep<<<5376, 256, 0, stream>>>(x, Wv, Wo, xb, WvT, Wob);
    // V = x @ Wv, written permuted (bf16)
    gemm_bt<true,  bf16 ><<<dim3(32, 16), 256, 0, stream>>>(xb, WvT, vperm);
    // y = Vp @ Wo^T  (fp32 output)
    gemm_bt<false, float><<<dim3(32, 16), 256, 0, stream>>>(vperm, Wob, out);
}